// Round 1
// 922.704 us; speedup vs baseline: 1.2493x; 1.2493x over previous
//
#include <hip/hip_runtime.h>

typedef float f32x4 __attribute__((ext_vector_type(4)));
typedef short bf16x8 __attribute__((ext_vector_type(8)));

#define DEVI __device__ __forceinline__

// ---------- constants (problem shape is fixed) ----------
constexpr int Bn = 2;          // batch
constexpr int Sn = 4096;       // seq
constexpr int Hn = 16;         // heads
constexpr int Dn = 128;        // head dim
constexpr int En = 2048;       // d_model = Hn*Dn
constexpr int Mtot = Bn * Sn;  // 8192 token rows

DEVI unsigned short f2bf(float f) {
  unsigned u = __float_as_uint(f);
  u += 0x7fffu + ((u >> 16) & 1u);
  return (unsigned short)(u >> 16);
}
DEVI float bf2f(unsigned short h) {
  return __uint_as_float(((unsigned)h) << 16);
}

DEVI void async16(const void* g, void* l) {
  __builtin_amdgcn_global_load_lds(
      (const __attribute__((address_space(1))) void*)g,
      (__attribute__((address_space(3))) void*)l, 16, 0, 0);
}

// ---------- fp32 -> bf16 convert ----------
__global__ void cvt_kernel(const float* __restrict__ in, ushort* __restrict__ out) {
  size_t i = ((size_t)blockIdx.x * 256 + threadIdx.x) * 4;
  float4 v = *(const float4*)&in[i];
  ushort4 o;
  o.x = f2bf(v.x); o.y = f2bf(v.y); o.z = f2bf(v.z); o.w = f2bf(v.w);
  *(ushort4*)&out[i] = o;
}

// ---------- RoPE in place on [Mtot, En] bf16, interleaved pairs ----------
// scale: extra multiplier folded into the output (1/sqrt(d)*log2e for Q, 1 for K)
__global__ void rope_kernel(ushort* __restrict__ Q, float scale) {
  int row = blockIdx.x;           // 0..Mtot-1
  int s = row & (Sn - 1);
  int t = threadIdx.x;
  size_t base = (size_t)row * En;
#pragma unroll
  for (int rep = 0; rep < 4; ++rep) {
    int p = rep * 256 + t;        // pair index 0..1023
    int e = p * 2;
    int pp = (e & (Dn - 1)) >> 1; // pair index within head, 0..63
    // inv_freq = 10000^(-pp/64) = exp2(-pp * log2(10000)/64)
    float inv = exp2f(-(float)pp * (13.287712379549449f / 64.0f));
    float ang = (float)s * inv;
    float c = cosf(ang), sn = sinf(ang);
    unsigned v = *(unsigned*)&Q[base + e];
    float q0 = bf2f((unsigned short)(v & 0xffffu));
    float q1 = bf2f((unsigned short)(v >> 16));
    float n0 = (q0 * c - q1 * sn) * scale;
    float n1 = (q1 * c + q0 * sn) * scale;
    unsigned outv = (unsigned)f2bf(n0) | ((unsigned)f2bf(n1) << 16);
    *(unsigned*)&Q[base + e] = outv;
  }
}

// ---------- GEMM: C[M,N] = A[M,K] * B[N,K]^T, bf16 in, fp32 acc ----------
// EPI 0: bf16 C row-major [Mtot, En]
// EPI 1: bf16 transposed V: Vt[(b*En + n)*Sn + s]  (m = b*Sn + s)
// EPI 2: fp32 C row-major
template <int EPI>
__global__ __launch_bounds__(256) void gemm_bt(const ushort* __restrict__ A,
                                               const ushort* __restrict__ Bm,
                                               void* __restrict__ Cv) {
  __shared__ ushort As[128 * 64];
  __shared__ ushort Bs[128 * 64];
  const int t = threadIdx.x;
  const int lane = t & 63, w = t >> 6;
  const int ln = lane & 15, gq = lane >> 4;
  const int m0 = blockIdx.y * 128, n0 = blockIdx.x * 128;
  const int rm = (w >> 1) * 64, rn = (w & 1) * 64;
  f32x4 acc[4][4] = {};

  for (int k0 = 0; k0 < En; k0 += 64) {
#pragma unroll
    for (int rep = 0; rep < 4; ++rep) {
      int c = rep * 256 + t;       // chunk 0..1023 (16B each)
      int row = c >> 3, c8 = c & 7;
      async16(&A[(size_t)(m0 + row) * En + k0 + c8 * 8],
              (char*)As + (rep * 256 + w * 64) * 16);
      async16(&Bm[(size_t)(n0 + row) * En + k0 + c8 * 8],
              (char*)Bs + (rep * 256 + w * 64) * 16);
    }
    __syncthreads();
#pragma unroll
    for (int kk = 0; kk < 64; kk += 32) {
      bf16x8 af[4], bf[4];
#pragma unroll
      for (int i = 0; i < 4; ++i)
        af[i] = *(const bf16x8*)&As[(rm + i * 16 + ln) * 64 + kk + gq * 8];
#pragma unroll
      for (int j = 0; j < 4; ++j)
        bf[j] = *(const bf16x8*)&Bs[(rn + j * 16 + ln) * 64 + kk + gq * 8];
#pragma unroll
      for (int i = 0; i < 4; ++i)
#pragma unroll
        for (int j = 0; j < 4; ++j)
          acc[i][j] = __builtin_amdgcn_mfma_f32_16x16x32_bf16(af[i], bf[j], acc[i][j], 0, 0, 0);
    }
    __syncthreads();
  }

  if constexpr (EPI == 0) {
    ushort* C = (ushort*)Cv;
#pragma unroll
    for (int i = 0; i < 4; ++i) {
      int row0 = m0 + rm + i * 16 + gq * 4;
#pragma unroll
      for (int j = 0; j < 4; ++j) {
        int col = n0 + rn + j * 16 + ln;
#pragma unroll
        for (int r = 0; r < 4; ++r)
          C[(size_t)(row0 + r) * En + col] = f2bf(acc[i][j][r]);
      }
    }
  } else if constexpr (EPI == 1) {
    ushort* Vt = (ushort*)Cv;
#pragma unroll
    for (int i = 0; i < 4; ++i) {
      int mrow = m0 + rm + i * 16 + gq * 4;   // token row (4 consecutive)
      int bb = mrow >> 12;                     // /Sn
      int ss = mrow & (Sn - 1);
#pragma unroll
      for (int j = 0; j < 4; ++j) {
        int col = n0 + rn + j * 16 + ln;       // e = h*128+d
        ushort4 pk;
        pk.x = f2bf(acc[i][j][0]); pk.y = f2bf(acc[i][j][1]);
        pk.z = f2bf(acc[i][j][2]); pk.w = f2bf(acc[i][j][3]);
        *(ushort4*)&Vt[((size_t)(bb * En + col)) * Sn + ss] = pk;
      }
    }
  } else {
    float* C = (float*)Cv;
#pragma unroll
    for (int i = 0; i < 4; ++i) {
      int row0 = m0 + rm + i * 16 + gq * 4;
#pragma unroll
      for (int j = 0; j < 4; ++j) {
        int col = n0 + rn + j * 16 + ln;
#pragma unroll
        for (int r = 0; r < 4; ++r)
          C[(size_t)(row0 + r) * En + col] = acc[i][j][r];
      }
    }
  }
}

// ---------- flash attention (causal), S^T formulation ----------
// Q: [Mtot, En] bf16 (post-RoPE, pre-scaled by 1/sqrt(d)*log2e).
// K: [Mtot, En] bf16 (post-RoPE). Vt: [B*En, Sn] bf16 (transposed V).
// Out Ab: [Mtot, En] bf16.
// Grid: (bh, qtile). qtile is REVERSED so the heaviest causal blocks dispatch
// first (LPT scheduling -> no straggler tail).
// Ks/Vs are XOR-swizzled (byte ^= (row&7)<<4): linear LDS dest for
// global_load_lds, inverse swizzle on the per-lane GLOBAL source address,
// same XOR applied on the ds_read side (technique #21).
__global__ __launch_bounds__(256) void flash_kernel(const ushort* __restrict__ Qb,
                                                    const ushort* __restrict__ Kb,
                                                    const ushort* __restrict__ Vt,
                                                    ushort* __restrict__ Ab) {
  __shared__ ushort Ks[64 * 128];   // [kv j][d], swizzled
  __shared__ ushort Vs[128 * 64];   // [d][kv j], swizzled
  __shared__ ushort Ps[4][32 * 72]; // per-wave P: [q i][kv j], pad 64->72
  const int t = threadIdx.x;
  const int lane = t & 63, w = t >> 6;
  const int ln = lane & 15, gq = lane >> 4;
  const int swz = (ln & 7) << 3;    // ushort-index XOR for swizzled reads
  const int q0 = (gridDim.y - 1 - blockIdx.y) * 128;  // heavy-first
  const int bh = blockIdx.x;
  const int b = bh >> 4, h = bh & 15;

  // Q fragments (B-operand): n = q row = q0 + w*32 + it*16 + ln; k = d
  bf16x8 qf[2][4];
#pragma unroll
  for (int it = 0; it < 2; ++it) {
    int qrow = q0 + w * 32 + it * 16 + ln;
    size_t base = ((size_t)(b * Sn + qrow)) * En + h * Dn;
#pragma unroll
    for (int ks = 0; ks < 4; ++ks)
      qf[it][ks] = *(const bf16x8*)&Qb[base + ks * 32 + gq * 8];
  }

  f32x4 o[8][2] = {};                 // O^T acc: [dt][it], row=d col=q
  float m_prev[2] = {-1e30f, -1e30f};
  float l_prev[2] = {0.f, 0.f};

  for (int j0 = 0; j0 <= q0 + 64; j0 += 64) {
    // stage K tile [64][128] and Vt tile [128][64], swizzled via source addr
#pragma unroll
    for (int rep = 0; rep < 4; ++rep) {
      int c = rep * 256 + t;
      int krow = c >> 4, kcs = c & 15;
      int kc = kcs ^ (krow & 7);          // inverse swizzle on global chunk
      async16(&Kb[((size_t)(b * Sn + j0 + krow)) * En + h * Dn + kc * 8],
              (char*)Ks + (rep * 256 + w * 64) * 16);
      int vrow = c >> 3, vcs = c & 7;
      int vc = vcs ^ (vrow & 7);
      async16(&Vt[((size_t)(b * En + h * Dn + vrow)) * Sn + j0 + vc * 8],
              (char*)Vs + (rep * 256 + w * 64) * 16);
    }
    __syncthreads();

    // waves whose q columns are entirely above this kv tile skip compute
    if (j0 <= q0 + w * 32 + 31) {
      // S^T tiles: C[m=j][n=i]
      f32x4 s[2][4] = {};
      __builtin_amdgcn_s_setprio(1);
#pragma unroll
      for (int jt = 0; jt < 4; ++jt) {
#pragma unroll
        for (int ks = 0; ks < 4; ++ks) {
          bf16x8 kf = *(const bf16x8*)&Ks[(((jt * 16 + ln) * 128 + ks * 32 + gq * 8)) ^ swz];
          s[0][jt] = __builtin_amdgcn_mfma_f32_16x16x32_bf16(kf, qf[0][ks], s[0][jt], 0, 0, 0);
          s[1][jt] = __builtin_amdgcn_mfma_f32_16x16x32_bf16(kf, qf[1][ks], s[1][jt], 0, 0, 0);
        }
      }
      __builtin_amdgcn_s_setprio(0);

      // online softmax per q column (each lane owns column i = ln)
#pragma unroll
      for (int it = 0; it < 2; ++it) {
        const int qbase = q0 + w * 32 + it * 16;  // wave-uniform min q row
        const int qrow = qbase + ln;
        float mx = -1e30f;
        if (j0 + 63 > qbase) {
          // diagonal tile: apply causal mask
#pragma unroll
          for (int jt = 0; jt < 4; ++jt)
#pragma unroll
            for (int r = 0; r < 4; ++r) {
              int j = j0 + jt * 16 + gq * 4 + r;
              float v = s[it][jt][r];
              if (j > qrow) v = -1e30f;
              s[it][jt][r] = v;
              mx = fmaxf(mx, v);
            }
        } else {
#pragma unroll
          for (int jt = 0; jt < 4; ++jt)
#pragma unroll
            for (int r = 0; r < 4; ++r)
              mx = fmaxf(mx, s[it][jt][r]);
        }
        mx = fmaxf(mx, __shfl_xor(mx, 16));
        mx = fmaxf(mx, __shfl_xor(mx, 32));
        // defer-max (T13): skip O/l rescale when max growth <= 8 (log2 domain)
        float mn;
        if (__all(mx - m_prev[it] <= 8.f)) {
          mn = m_prev[it];
        } else {
          mn = fmaxf(m_prev[it], mx);
          float alpha = exp2f(m_prev[it] - mn);
          m_prev[it] = mn;
          l_prev[it] *= alpha;
#pragma unroll
          for (int dt = 0; dt < 8; ++dt) o[dt][it] *= alpha;
        }
        float sum = 0.f;
#pragma unroll
        for (int jt = 0; jt < 4; ++jt) {
#pragma unroll
          for (int r = 0; r < 4; ++r) {
            float p = exp2f(s[it][jt][r] - mn);
            s[it][jt][r] = p;
            sum += p;
          }
        }
        sum += __shfl_xor(sum, 16);
        sum += __shfl_xor(sum, 32);
        l_prev[it] += sum;
        // write P (bf16) to wave-private LDS: row = q i, col = kv j
#pragma unroll
        for (int jt = 0; jt < 4; ++jt) {
          ushort4 pk;
          pk.x = f2bf(s[it][jt][0]); pk.y = f2bf(s[it][jt][1]);
          pk.z = f2bf(s[it][jt][2]); pk.w = f2bf(s[it][jt][3]);
          *(ushort4*)&Ps[w][(it * 16 + ln) * 72 + jt * 16 + gq * 4] = pk;
        }
      }

      // PV: O^T[d][i] += sum_j Vs[d][j] * P[i][j]
      __builtin_amdgcn_s_setprio(1);
#pragma unroll
      for (int ksj = 0; ksj < 2; ++ksj) {
        bf16x8 pf[2];
#pragma unroll
        for (int it = 0; it < 2; ++it)
          pf[it] = *(const bf16x8*)&Ps[w][(it * 16 + ln) * 72 + ksj * 32 + gq * 8];
#pragma unroll
        for (int dt = 0; dt < 8; ++dt) {
          bf16x8 vf = *(const bf16x8*)&Vs[(((dt * 16 + ln) * 64 + ksj * 32 + gq * 8)) ^ swz];
          o[dt][0] = __builtin_amdgcn_mfma_f32_16x16x32_bf16(vf, pf[0], o[dt][0], 0, 0, 0);
          o[dt][1] = __builtin_amdgcn_mfma_f32_16x16x32_bf16(vf, pf[1], o[dt][1], 0, 0, 0);
        }
      }
      __builtin_amdgcn_s_setprio(0);
    }
    __syncthreads();
  }

  // epilogue: normalize by 1/l, write Ab[b, qrow, h*128 + d]
#pragma unroll
  for (int it = 0; it < 2; ++it) {
    float inv = 1.f / l_prev[it];
    int qrow = q0 + w * 32 + it * 16 + ln;
    size_t base = ((size_t)(b * Sn + qrow)) * En + h * Dn;
#pragma unroll
    for (int dt = 0; dt < 8; ++dt) {
      ushort4 pk;
      pk.x = f2bf(o[dt][it][0] * inv);
      pk.y = f2bf(o[dt][it][1] * inv);
      pk.z = f2bf(o[dt][it][2] * inv);
      pk.w = f2bf(o[dt][it][3] * inv);
      *(ushort4*)&Ab[base + dt * 16 + gq * 4] = pk;
    }
  }
}

extern "C" void kernel_launch(void* const* d_in, const int* in_sizes, int n_in,
                              void* d_out, int out_size, void* d_ws, size_t ws_size,
                              hipStream_t stream) {
  const float* x  = (const float*)d_in[0];
  const float* Wq = (const float*)d_in[1];
  const float* Wk = (const float*)d_in[2];
  const float* Wv = (const float*)d_in[3];
  const float* Wo = (const float*)d_in[4];

  char* ws = (char*)d_ws;
  ushort* xb  = (ushort*)(ws + 0);           // 32 MiB  [Mtot, En]
  ushort* wqb = (ushort*)(ws + 33554432);    // 8 MiB
  ushort* wkb = (ushort*)(ws + 41943040);
  ushort* wvb = (ushort*)(ws + 50331648);
  ushort* wob = (ushort*)(ws + 58720256);
  ushort* Qb  = (ushort*)(ws + 67108864);    // 32 MiB
  ushort* Kb  = (ushort*)(ws + 100663296);   // 32 MiB
  ushort* Vt  = (ushort*)(ws + 134217728);   // 32 MiB  [B*En, Sn]
  ushort* Ab  = xb;                           // alias: xb dead after V GEMM

  // converts
  cvt_kernel<<<dim3(Mtot * En / 1024), 256, 0, stream>>>(x, xb);
  cvt_kernel<<<dim3(En * En / 1024), 256, 0, stream>>>(Wq, wqb);
  cvt_kernel<<<dim3(En * En / 1024), 256, 0, stream>>>(Wk, wkb);
  cvt_kernel<<<dim3(En * En / 1024), 256, 0, stream>>>(Wv, wvb);
  cvt_kernel<<<dim3(En * En / 1024), 256, 0, stream>>>(Wo, wob);

  dim3 ggrid(En / 128, Mtot / 128);
  gemm_bt<0><<<ggrid, 256, 0, stream>>>(xb, wqb, (void*)Qb);
  gemm_bt<0><<<ggrid, 256, 0, stream>>>(xb, wkb, (void*)Kb);
  gemm_bt<1><<<ggrid, 256, 0, stream>>>(xb, wvb, (void*)Vt);

  // RoPE: fold softmax scale (1/sqrt(d) * log2e) into Q here
  rope_kernel<<<dim3(Mtot), 256, 0, stream>>>(Qb, 0.08838834764831845f * 1.4426950408889634f);
  rope_kernel<<<dim3(Mtot), 256, 0, stream>>>(Kb, 1.0f);

  flash_kernel<<<dim3(Bn * Hn, Sn / 128), 256, 0, stream>>>(Qb, Kb, Vt, Ab);

  gemm_bt<2><<<ggrid, 256, 0, stream>>>(Ab, wob, d_out);
}